// Round 12
// baseline (72.296 us; speedup 1.0000x reference)
//
#include <hip/hip_runtime.h>

// LTPE: y(p) = x(p) - sum_j w_j * x(p + off_j), zero-padded borders,
// then instance-norm over HxW per image: (y - mean) * rsqrt(var + 4e-5).
// (The reference's out = 0.5*y + 0.5; instance norm is affine-invariant,
//  with eps folding 1e-5 -> 4e-5.)
//
// Recompute skeleton (round-11, 69.7us best). Round-12 change: pass 2
// de-interleaves loads and stores. CDNA's single in-order vmcnt counter
// means a load's data can't be confirmed until every OLDER outstanding
// store acks (rounds 9/10: store-interleaved stencil ran 2.6x over its
// traffic floor). New pass 2: NBLK2=128, each block loads its 10 rows
// (8 + 2 halo) up-front into registers, runs the stats reduce under the
// load latency, then computes + nt-stores 8 rows -- every store younger
// than every load, so no consume waits on store acks.

#define HH 1024
#define WW 1024
#define HW (HH * WW)
#define NIMG 32
#define NBLK1 64                 // pass-1 blocks per image (pure read)
#define RPB1 (HH / NBLK1)        // 16 rows per block
#define NBLK2 128                // pass-2 blocks per image
#define RPB2 (HH / NBLK2)        // 8 rows per block
#define TPB 256                  // = WW/4 float4 columns per row

typedef float vfloat4 __attribute__((ext_vector_type(4)));

// weights: j=0..7 -> 2^j/255, offsets (dy,dx):
// j0 (0,-1), j1 (1,-1), j2 (1,0), j3 (1,1), j4 (0,1), j5 (-1,1), j6 (-1,0), j7 (-1,-1)
__device__ __forceinline__ void compute_y(const float* up, const float* mid,
                                          const float* dn, float* y) {
    const float w0 = 1.f / 255.f,  w1 = 2.f / 255.f,  w2 = 4.f / 255.f,
                w3 = 8.f / 255.f,  w4 = 16.f / 255.f, w5 = 32.f / 255.f,
                w6 = 64.f / 255.f, w7 = 128.f / 255.f;
#pragma unroll
    for (int k = 0; k < 4; ++k) {
        float s = w0 * mid[k] + w4 * mid[k + 2]
                + w1 * dn[k]  + w2 * dn[k + 1] + w3 * dn[k + 2]
                + w7 * up[k]  + w6 * up[k + 1] + w5 * up[k + 2];
        y[k] = mid[k + 1] - s;
    }
}

// buf[0]=left halo, buf[1..4]=vfloat4, buf[5]=right halo; zeros out of range
__device__ __forceinline__ void load_row_g(const float* __restrict__ base,
                                           int r, int c, float* buf) {
    if (r < 0 || r >= HH) {
#pragma unroll
        for (int k = 0; k < 6; ++k) buf[k] = 0.f;
        return;
    }
    const float* row = base + (size_t)r * WW;
    const vfloat4 v = reinterpret_cast<const vfloat4*>(row)[c];
    buf[0] = (c > 0) ? row[4 * c - 1] : 0.f;
    buf[1] = v.x; buf[2] = v.y; buf[3] = v.z; buf[4] = v.w;
    buf[5] = (c < TPB - 1) ? row[4 * c + 4] : 0.f;
}

// ---------------- pass 1: pure-read stencil -> stats partials ----------------
__global__ __launch_bounds__(TPB) void ltpe_stats(const float* __restrict__ x,
                                                  float* __restrict__ partials) {
    const int img = blockIdx.x / NBLK1;
    const int blk = blockIdx.x % NBLK1;
    const int c = threadIdx.x;
    const float* base = x + (size_t)img * HW;
    const int r0 = blk * RPB1;

    // rolling 4-row register pipeline (2-deep prefetch), fully unrolled
    float buf[4][6];
    load_row_g(base, r0 - 1, c, buf[0]);
    load_row_g(base, r0,     c, buf[1]);
    load_row_g(base, r0 + 1, c, buf[2]);
    load_row_g(base, r0 + 2, c, buf[3]);

    float s = 0.f, ss = 0.f;
#pragma unroll
    for (int i = 0; i < RPB1; ++i) {
        const int r = r0 + i;
        float y[4];
        compute_y(buf[i & 3], buf[(i + 1) & 3], buf[(i + 2) & 3], y);
#pragma unroll
        for (int k = 0; k < 4; ++k) { s += y[k]; ss = fmaf(y[k], y[k], ss); }
        if (i + 2 < RPB1)  // row r+3 serves as dn in iter i+2
            load_row_g(base, r + 3, c, buf[i & 3]);
    }

    // block reduction: wave64 shuffle, then LDS across 4 waves
#pragma unroll
    for (int off = 32; off > 0; off >>= 1) {
        s += __shfl_down(s, off);
        ss += __shfl_down(ss, off);
    }
    __shared__ float sh[8];
    const int wave = threadIdx.x >> 6;
    const int lane = threadIdx.x & 63;
    if (lane == 0) { sh[wave] = s; sh[4 + wave] = ss; }
    __syncthreads();
    if (threadIdx.x == 0) {
        partials[img * NBLK1 + blk] = sh[0] + sh[1] + sh[2] + sh[3];
        partials[NIMG * NBLK1 + img * NBLK1 + blk] = sh[4] + sh[5] + sh[6] + sh[7];
    }
}

// ----- pass 2: all loads up-front, reduce under latency, then compute+store -----
__global__ __launch_bounds__(TPB) void ltpe_norm(const float* __restrict__ x,
                                                 const float* __restrict__ partials,
                                                 float* __restrict__ out) {
    const int img = blockIdx.x / NBLK2;
    const int blk = blockIdx.x % NBLK2;
    const int c = threadIdx.x;
    const float* base = x + (size_t)img * HW;
    const int r0 = blk * RPB2;

    // load ALL rows this block needs (8 + 2 halo) before any store is issued
    float buf[RPB2 + 2][6];
#pragma unroll
    for (int j = 0; j < RPB2 + 2; ++j)
        load_row_g(base, r0 - 1 + j, c, buf[j]);

    // redundant per-block final reduce of this image's 64 partials (one wave);
    // overlaps the outstanding row loads above.
    __shared__ float sh_stats[2];
    if (threadIdx.x < 64) {
        const int lane = threadIdx.x;
        double S = (double)partials[img * NBLK1 + lane];
        double SS = (double)partials[NIMG * NBLK1 + img * NBLK1 + lane];
#pragma unroll
        for (int off = 32; off > 0; off >>= 1) {
            S += __shfl_down(S, off);
            SS += __shfl_down(SS, off);
        }
        if (lane == 0) {
            const double N = (double)HW;
            const double m = S / N;
            const double var = SS / N - m * m;
            sh_stats[0] = (float)m;
            sh_stats[1] = (float)(1.0 / sqrt(var + 4e-5)); // 4*eps folds the 0.5
        }
    }
    __syncthreads();
    const float mean = sh_stats[0];
    const float scale = sh_stats[1];

    float* obase = out + (size_t)img * HW;

#pragma unroll
    for (int i = 0; i < RPB2; ++i) {
        const int r = r0 + i;
        float y[4];
        compute_y(buf[i], buf[i + 1], buf[i + 2], y);
        vfloat4 o;
        o.x = (y[0] - mean) * scale;
        o.y = (y[1] - mean) * scale;
        o.z = (y[2] - mean) * scale;
        o.w = (y[3] - mean) * scale;
        // nt streaming store; all stores younger than all loads in this wave
        __builtin_nontemporal_store(
            o, reinterpret_cast<vfloat4*>(obase + (size_t)r * WW) + c);
    }
}

extern "C" void kernel_launch(void* const* d_in, const int* in_sizes, int n_in,
                              void* d_out, int out_size, void* d_ws, size_t ws_size,
                              hipStream_t stream) {
    const float* x = (const float*)d_in[0];
    float* out = (float*)d_out;
    float* partials = (float*)d_ws; // [NIMG*NBLK1 sums][NIMG*NBLK1 sumsqs]

    ltpe_stats<<<NIMG * NBLK1, TPB, 0, stream>>>(x, partials);
    ltpe_norm<<<NIMG * NBLK2, TPB, 0, stream>>>(x, partials, out);
}